// Round 1
// baseline (129.388 us; speedup 1.0000x reference)
//
#include <hip/hip_runtime.h>

#define T_DIM 256
#define C_DIM 384
#define H_DIM 64

typedef __attribute__((ext_vector_type(4))) float f32x4;
typedef __attribute__((ext_vector_type(8))) short bf16x8;
typedef unsigned short u16;

// fp32 -> bf16 round-to-nearest-even (finite inputs)
__device__ __forceinline__ u16 f2b(float f) {
  unsigned u = __float_as_uint(f);
  u = (u + 0x7FFFu + ((u >> 16) & 1u)) >> 16;
  return (u16)u;
}

// One block per batch. 512 threads = 8 waves.
// Phase 1: QKV = x_b @ [Wq|Wk|Wv]  (M=256, N=192, K=384) via 16x16x32 bf16 MFMA.
// Phase 2: per-wave flash attention over causal kv tiles of 64, all operands in LDS.
__global__ __launch_bounds__(512, 2)
void head_fused(const float* __restrict__ x,
                const float* __restrict__ Wk,
                const float* __restrict__ Wq,
                const float* __restrict__ Wv,
                float* __restrict__ out)
{
  __shared__ u16 qs[T_DIM][H_DIM];   // 32 KB  Q[t][h] bf16
  __shared__ u16 ks[T_DIM][H_DIM];   // 32 KB  K[t][h] bf16
  __shared__ u16 vT[H_DIM][T_DIM];   // 32 KB  V^T[h][t] bf16
  __shared__ u16 un[16384];          // 32 KB  phase1: xs[256][32]+wsT[192][32]; phase2: P slabs [8][32][64]

  u16 (*xs)[32]  = reinterpret_cast<u16(*)[32]>(un);         // x tile [256][32]
  u16 (*wsT)[32] = reinterpret_cast<u16(*)[32]>(un + 8192);  // W^T tile [192][32]

  const int tid  = threadIdx.x;
  const int wv   = tid >> 6;     // wave 0..7
  const int lane = tid & 63;
  const int g    = lane >> 4;    // 0..3
  const int lr   = lane & 15;    // 0..15
  const int b    = blockIdx.x;

  const float* xb = x + (size_t)b * (T_DIM * C_DIM);

  // ---------------- Phase 1: QKV projection ----------------
  f32x4 acc[2][12];
#pragma unroll
  for (int mi = 0; mi < 2; ++mi)
#pragma unroll
    for (int nj = 0; nj < 12; ++nj)
      acc[mi][nj] = (f32x4){0.f, 0.f, 0.f, 0.f};

  for (int kk = 0; kk < C_DIM; kk += 32) {
    __syncthreads();   // previous iteration's fragment reads done
    // stage x tile [256][32] fp32->bf16 (2048 float4, 4 per thread)
#pragma unroll
    for (int it = 0; it < 4; ++it) {
      int idx = tid + it * 512;
      int row = idx >> 3;            // 0..255
      int c4  = (idx & 7) * 4;       // 0..28
      f32x4 f = *reinterpret_cast<const f32x4*>(xb + row * C_DIM + kk + c4);
      unsigned p0 = (unsigned)f2b(f[0]) | ((unsigned)f2b(f[1]) << 16);
      unsigned p1 = (unsigned)f2b(f[2]) | ((unsigned)f2b(f[3]) << 16);
      uint2 pv; pv.x = p0; pv.y = p1;
      *reinterpret_cast<uint2*>(&xs[row][c4]) = pv;
    }
    // stage W^T tile [192][32]: rows 0-63 = Wq, 64-127 = Wk, 128-191 = Wv
    // (1536 float4 from W rows, 3 per thread; transposed scalar writes)
#pragma unroll
    for (int it = 0; it < 3; ++it) {
      int idx = tid + it * 512;      // 0..1535
      int cc  = idx / 48;            // k within tile 0..31
      int h4  = idx - cc * 48;       // 0..47
      int seg = h4 >> 4;             // 0:Q 1:K 2:V
      int hh  = (h4 & 15) * 4;       // 0..60
      const float* Wp = (seg == 0) ? Wq : (seg == 1) ? Wk : Wv;
      f32x4 f = *reinterpret_cast<const f32x4*>(Wp + (kk + cc) * H_DIM + hh);
      int nb = seg * 64 + hh;
      wsT[nb + 0][cc] = f2b(f[0]);
      wsT[nb + 1][cc] = f2b(f[1]);
      wsT[nb + 2][cc] = f2b(f[2]);
      wsT[nb + 3][cc] = f2b(f[3]);
    }
    __syncthreads();

    // MFMA: wave wv computes rows [wv*32, wv*32+32), all 192 N cols
    bf16x8 afr[2];
#pragma unroll
    for (int mi = 0; mi < 2; ++mi)
      afr[mi] = *reinterpret_cast<const bf16x8*>(&xs[wv * 32 + mi * 16 + lr][g * 8]);
#pragma unroll
    for (int nj = 0; nj < 12; ++nj) {
      bf16x8 bfr = *reinterpret_cast<const bf16x8*>(&wsT[nj * 16 + lr][g * 8]);
#pragma unroll
      for (int mi = 0; mi < 2; ++mi)
        acc[mi][nj] = __builtin_amdgcn_mfma_f32_16x16x32_bf16(afr[mi], bfr, acc[mi][nj], 0, 0, 0);
    }
  }

  // scatter QKV fragments into LDS (D layout: row = 4g+e, col = lr)
#pragma unroll
  for (int mi = 0; mi < 2; ++mi)
#pragma unroll
    for (int nj = 0; nj < 12; ++nj)
#pragma unroll
      for (int e = 0; e < 4; ++e) {
        int r = wv * 32 + mi * 16 + g * 4 + e;
        int n = nj * 16 + lr;
        u16 val = f2b(acc[mi][nj][e]);
        if (n < 64)       qs[r][n] = val;
        else if (n < 128) ks[r][n - 64] = val;
        else              vT[n - 128][r] = val;
      }
  __syncthreads();

  // ---------------- Phase 2: causal flash attention ----------------
  const int r0   = wv * 32;
  const int jmax = wv >> 1;          // last kv tile this wave needs
  u16* pw = un + wv * 2048;          // per-wave P slab [32][64]

  bf16x8 qf[2][2];
#pragma unroll
  for (int mi = 0; mi < 2; ++mi)
#pragma unroll
    for (int kb = 0; kb < 2; ++kb)
      qf[mi][kb] = *reinterpret_cast<const bf16x8*>(&qs[r0 + mi * 16 + lr][kb * 32 + g * 8]);

  f32x4 o[2][4];
  float m_run[2][4], l_run[2][4];
#pragma unroll
  for (int mi = 0; mi < 2; ++mi) {
#pragma unroll
    for (int e = 0; e < 4; ++e) { m_run[mi][e] = -__builtin_inff(); l_run[mi][e] = 0.f; }
#pragma unroll
    for (int nh = 0; nh < 4; ++nh) o[mi][nh] = (f32x4){0.f, 0.f, 0.f, 0.f};
  }

  for (int j = 0; j <= jmax; ++j) {
    // S tile [32][64] = Q rows x K tile^T
    f32x4 s[2][4];
#pragma unroll
    for (int mi = 0; mi < 2; ++mi)
#pragma unroll
      for (int nj = 0; nj < 4; ++nj)
        s[mi][nj] = (f32x4){0.f, 0.f, 0.f, 0.f};
#pragma unroll
    for (int kb = 0; kb < 2; ++kb) {
#pragma unroll
      for (int nj = 0; nj < 4; ++nj) {
        bf16x8 kf = *reinterpret_cast<const bf16x8*>(&ks[j * 64 + nj * 16 + lr][kb * 32 + g * 8]);
#pragma unroll
        for (int mi = 0; mi < 2; ++mi)
          s[mi][nj] = __builtin_amdgcn_mfma_f32_16x16x32_bf16(qf[mi][kb], kf, s[mi][nj], 0, 0, 0);
      }
    }
    // scale + causal mask + per-row max (rows live per (mi,e); cols across 16-lane group + nj)
    float pm[2][4];
#pragma unroll
    for (int mi = 0; mi < 2; ++mi)
#pragma unroll
      for (int e = 0; e < 4; ++e) pm[mi][e] = -__builtin_inff();
#pragma unroll
    for (int mi = 0; mi < 2; ++mi)
#pragma unroll
      for (int nj = 0; nj < 4; ++nj)
#pragma unroll
        for (int e = 0; e < 4; ++e) {
          float v = s[mi][nj][e] * 0.125f;
          int r  = r0 + mi * 16 + g * 4 + e;
          int kv = j * 64 + nj * 16 + lr;
          v = (kv > r) ? -__builtin_inff() : v;
          s[mi][nj][e] = v;
          pm[mi][e] = fmaxf(pm[mi][e], v);
        }
#pragma unroll
    for (int off = 1; off < 16; off <<= 1)
#pragma unroll
      for (int mi = 0; mi < 2; ++mi)
#pragma unroll
        for (int e = 0; e < 4; ++e)
          pm[mi][e] = fmaxf(pm[mi][e], __shfl_xor(pm[mi][e], off));

    // online-softmax update
    float rs[2][4];
#pragma unroll
    for (int mi = 0; mi < 2; ++mi)
#pragma unroll
      for (int e = 0; e < 4; ++e) {
        float mn = fmaxf(m_run[mi][e], pm[mi][e]);
        float alpha = __expf(m_run[mi][e] - mn);   // first tile: exp(-inf)=0
        m_run[mi][e] = mn;
        l_run[mi][e] *= alpha;
        rs[mi][e] = 0.f;
#pragma unroll
        for (int nh = 0; nh < 4; ++nh) o[mi][nh][e] *= alpha;
      }
#pragma unroll
    for (int mi = 0; mi < 2; ++mi)
#pragma unroll
      for (int nj = 0; nj < 4; ++nj)
#pragma unroll
        for (int e = 0; e < 4; ++e) {
          float p = __expf(s[mi][nj][e] - m_run[mi][e]);  // masked: exp(-inf)=0
          s[mi][nj][e] = p;
          rs[mi][e] += p;
        }
#pragma unroll
    for (int off = 1; off < 16; off <<= 1)
#pragma unroll
      for (int mi = 0; mi < 2; ++mi)
#pragma unroll
        for (int e = 0; e < 4; ++e)
          rs[mi][e] += __shfl_xor(rs[mi][e], off);
#pragma unroll
    for (int mi = 0; mi < 2; ++mi)
#pragma unroll
      for (int e = 0; e < 4; ++e) l_run[mi][e] += rs[mi][e];

    // write P tile to wave-private slab (D layout -> row-major [32][64])
#pragma unroll
    for (int mi = 0; mi < 2; ++mi)
#pragma unroll
      for (int nj = 0; nj < 4; ++nj)
#pragma unroll
        for (int e = 0; e < 4; ++e) {
          int rr = mi * 16 + g * 4 + e;
          int cc = nj * 16 + lr;
          pw[rr * 64 + cc] = f2b(s[mi][nj][e]);
        }
    // wave-local LDS fence (no __syncthreads here: waves have divergent j-trip counts)
    asm volatile("s_waitcnt lgkmcnt(0)" ::: "memory");

    // O += P @ V_tile
#pragma unroll
    for (int kb = 0; kb < 2; ++kb) {
      bf16x8 pf[2];
#pragma unroll
      for (int mi = 0; mi < 2; ++mi)
        pf[mi] = *reinterpret_cast<const bf16x8*>(&pw[(mi * 16 + lr) * 64 + kb * 32 + g * 8]);
#pragma unroll
      for (int nh = 0; nh < 4; ++nh) {
        bf16x8 vf = *reinterpret_cast<const bf16x8*>(&vT[nh * 16 + lr][j * 64 + kb * 32 + g * 8]);
#pragma unroll
        for (int mi = 0; mi < 2; ++mi)
          o[mi][nh] = __builtin_amdgcn_mfma_f32_16x16x32_bf16(pf[mi], vf, o[mi][nh], 0, 0, 0);
      }
    }
  }

  // epilogue: normalize and store fp32
  float* ob = out + (size_t)b * (T_DIM * H_DIM);
#pragma unroll
  for (int mi = 0; mi < 2; ++mi)
#pragma unroll
    for (int nh = 0; nh < 4; ++nh)
#pragma unroll
      for (int e = 0; e < 4; ++e) {
        int r = r0 + mi * 16 + g * 4 + e;
        int h = nh * 16 + lr;
        ob[r * H_DIM + h] = o[mi][nh][e] / l_run[mi][e];
      }
}

extern "C" void kernel_launch(void* const* d_in, const int* in_sizes, int n_in,
                              void* d_out, int out_size, void* d_ws, size_t ws_size,
                              hipStream_t stream) {
  const float* x  = (const float*)d_in[0];
  const float* Wk = (const float*)d_in[1];
  const float* Wq = (const float*)d_in[2];
  const float* Wv = (const float*)d_in[3];
  float* out = (float*)d_out;
  int B = in_sizes[0] / (T_DIM * C_DIM);   // 512
  head_fused<<<dim3(B), dim3(512), 0, stream>>>(x, Wk, Wq, Wv, out);
}

// Round 2
// 82.636 us; speedup vs baseline: 1.5658x; 1.5658x over previous
//
#include <hip/hip_runtime.h>

#define T_DIM 256
#define C_DIM 384
#define H_DIM 64

typedef __attribute__((ext_vector_type(4))) float f32x4;
typedef __attribute__((ext_vector_type(8))) short bf16x8;
typedef unsigned short u16;

// fp32 -> bf16 round-to-nearest-even (finite inputs)
__device__ __forceinline__ u16 f2b(float f) {
  unsigned u = __float_as_uint(f);
  u = (u + 0x7FFFu + ((u >> 16) & 1u)) >> 16;
  return (u16)u;
}

// Swizzled element offsets (u16 units). Both writes and reads go through these,
// so the permutation is a consistent involution per tile.
// 128B-row tiles (qs, ks, P slab): spread the 8 16B slots of a row pair-free.
__device__ __forceinline__ int sw64(int r, int c)  { return r * 64  + (c ^ ((r & 7) << 3)); }
// 512B-row tile (vT[h][t]): same idea on the low 128B window.
__device__ __forceinline__ int sw256(int h, int t) { return h * 256 + (t ^ ((h & 7) << 3)); }
// 64B-row tiles (xs, wsT): 4 slots; combine with the row bank-half bit -> 8 distinct quads.
__device__ __forceinline__ int sw32(int r, int c)  { return r * 32  + (c ^ (((r >> 1) & 3) << 3)); }

// One block per batch. 512 threads = 8 waves.
// Phase 1: QKV = x_b @ [Wq|Wk|Wv]  (M=256, N=192, K=384) via 16x16x32 bf16 MFMA.
// Phase 2: per-wave flash attention over causal kv tiles of 64, all operands in LDS.
__global__ __launch_bounds__(512, 2)
void head_fused(const float* __restrict__ x,
                const float* __restrict__ Wk,
                const float* __restrict__ Wq,
                const float* __restrict__ Wv,
                float* __restrict__ out)
{
  __shared__ u16 qs[T_DIM * H_DIM];   // 32 KB  Q[t][h] bf16  (sw64)
  __shared__ u16 ks[T_DIM * H_DIM];   // 32 KB  K[t][h] bf16  (sw64)
  __shared__ u16 vT[H_DIM * T_DIM];   // 32 KB  V^T[h][t] bf16 (sw256)
  __shared__ u16 un[16384];           // 32 KB  phase1: xs[256][32]+wsT[192][32]; phase2: P slabs

  u16* xs  = un;          // [256][32] sw32
  u16* wsT = un + 8192;   // [192][32] sw32 (rows 0-63 Wq, 64-127 Wk, 128-191 Wv)

  const int tid  = threadIdx.x;
  const int wv   = tid >> 6;
  const int lane = tid & 63;
  const int g    = lane >> 4;
  const int lr   = lane & 15;
  const int b    = blockIdx.x;

  const float* xb = x + (size_t)b * (T_DIM * C_DIM);

  // ---------------- Phase 1: QKV projection ----------------
  // per-thread loop-invariant staging coordinates
  int xr[4], xc[4];
#pragma unroll
  for (int it = 0; it < 4; ++it) {
    int idx = tid + it * 512;
    xr[it] = idx >> 3;
    xc[it] = (idx & 7) * 4;
  }
  int wcc[3], wnb[3];
  const float* wptr[3];
#pragma unroll
  for (int it = 0; it < 3; ++it) {
    int idx = tid + it * 512;          // 0..1535
    int cc  = idx / 48;                // k within tile 0..31
    int h4  = idx - cc * 48;           // 0..47
    int seg = h4 >> 4;                 // 0:Q 1:K 2:V
    int hh  = (h4 & 15) * 4;
    wcc[it] = cc;
    wnb[it] = seg * 64 + hh;
    wptr[it] = ((seg == 0) ? Wq : (seg == 1) ? Wk : Wv) + hh;
  }

  f32x4 acc[2][12];
#pragma unroll
  for (int mi = 0; mi < 2; ++mi)
#pragma unroll
    for (int nj = 0; nj < 12; ++nj)
      acc[mi][nj] = (f32x4){0.f, 0.f, 0.f, 0.f};

  // prefetch first tiles into registers
  f32x4 px[4], pwv[3];
#pragma unroll
  for (int it = 0; it < 4; ++it)
    px[it] = *reinterpret_cast<const f32x4*>(xb + xr[it] * C_DIM + xc[it]);
#pragma unroll
  for (int it = 0; it < 3; ++it)
    pwv[it] = *reinterpret_cast<const f32x4*>(wptr[it] + wcc[it] * H_DIM);

  for (int kt = 0; kt < 12; ++kt) {
    __syncthreads();   // previous iteration's fragment reads done
    // write staged registers to LDS (swizzled)
#pragma unroll
    for (int it = 0; it < 4; ++it) {
      unsigned p0 = (unsigned)f2b(px[it][0]) | ((unsigned)f2b(px[it][1]) << 16);
      unsigned p1 = (unsigned)f2b(px[it][2]) | ((unsigned)f2b(px[it][3]) << 16);
      uint2 pv; pv.x = p0; pv.y = p1;
      *reinterpret_cast<uint2*>(&xs[sw32(xr[it], xc[it])]) = pv;
    }
#pragma unroll
    for (int it = 0; it < 3; ++it) {
      wsT[sw32(wnb[it] + 0, wcc[it])] = f2b(pwv[it][0]);
      wsT[sw32(wnb[it] + 1, wcc[it])] = f2b(pwv[it][1]);
      wsT[sw32(wnb[it] + 2, wcc[it])] = f2b(pwv[it][2]);
      wsT[sw32(wnb[it] + 3, wcc[it])] = f2b(pwv[it][3]);
    }
    // prefetch next K-chunk (latency hides under the MFMA section)
    if (kt < 11) {
      int kk = (kt + 1) * 32;
#pragma unroll
      for (int it = 0; it < 4; ++it)
        px[it] = *reinterpret_cast<const f32x4*>(xb + xr[it] * C_DIM + kk + xc[it]);
#pragma unroll
      for (int it = 0; it < 3; ++it)
        pwv[it] = *reinterpret_cast<const f32x4*>(wptr[it] + (kk + wcc[it]) * H_DIM);
    }
    __syncthreads();

    // MFMA: wave wv computes rows [wv*32, wv*32+32), all 192 N cols
    bf16x8 afr[2];
#pragma unroll
    for (int mi = 0; mi < 2; ++mi)
      afr[mi] = *reinterpret_cast<const bf16x8*>(&xs[sw32(wv * 32 + mi * 16 + lr, g * 8)]);
#pragma unroll
    for (int nj = 0; nj < 12; ++nj) {
      bf16x8 bfr = *reinterpret_cast<const bf16x8*>(&wsT[sw32(nj * 16 + lr, g * 8)]);
#pragma unroll
      for (int mi = 0; mi < 2; ++mi)
        acc[mi][nj] = __builtin_amdgcn_mfma_f32_16x16x32_bf16(afr[mi], bfr, acc[mi][nj], 0, 0, 0);
    }
  }

  // scatter QKV fragments into LDS (D layout: row = 4g+e, col = lr), swizzled
#pragma unroll
  for (int mi = 0; mi < 2; ++mi)
#pragma unroll
    for (int nj = 0; nj < 12; ++nj)
#pragma unroll
      for (int e = 0; e < 4; ++e) {
        int r = wv * 32 + mi * 16 + g * 4 + e;
        int n = nj * 16 + lr;
        u16 val = f2b(acc[mi][nj][e]);
        if (n < 64)       qs[sw64(r, n)] = val;
        else if (n < 128) ks[sw64(r, n - 64)] = val;
        else              vT[sw256(n - 128, r)] = val;
      }
  __syncthreads();

  // ---------------- Phase 2: causal flash attention ----------------
  const int r0   = wv * 32;
  const int jmax = wv >> 1;          // last kv tile this wave needs
  u16* pw = un + wv * 2048;          // per-wave P slab [32][64] sw64

  bf16x8 qf[2][2];
#pragma unroll
  for (int mi = 0; mi < 2; ++mi)
#pragma unroll
    for (int kb = 0; kb < 2; ++kb)
      qf[mi][kb] = *reinterpret_cast<const bf16x8*>(&qs[sw64(r0 + mi * 16 + lr, kb * 32 + g * 8)]);

  f32x4 o[2][4];
  float m_run[2][4], l_run[2][4];
#pragma unroll
  for (int mi = 0; mi < 2; ++mi) {
#pragma unroll
    for (int e = 0; e < 4; ++e) { m_run[mi][e] = -__builtin_inff(); l_run[mi][e] = 0.f; }
#pragma unroll
    for (int nh = 0; nh < 4; ++nh) o[mi][nh] = (f32x4){0.f, 0.f, 0.f, 0.f};
  }

  for (int j = 0; j <= jmax; ++j) {
    // S tile [32][64] = Q rows x K tile^T
    f32x4 s[2][4];
#pragma unroll
    for (int mi = 0; mi < 2; ++mi)
#pragma unroll
      for (int nj = 0; nj < 4; ++nj)
        s[mi][nj] = (f32x4){0.f, 0.f, 0.f, 0.f};
#pragma unroll
    for (int kb = 0; kb < 2; ++kb) {
#pragma unroll
      for (int nj = 0; nj < 4; ++nj) {
        bf16x8 kf = *reinterpret_cast<const bf16x8*>(&ks[sw64(j * 64 + nj * 16 + lr, kb * 32 + g * 8)]);
#pragma unroll
        for (int mi = 0; mi < 2; ++mi)
          s[mi][nj] = __builtin_amdgcn_mfma_f32_16x16x32_bf16(qf[mi][kb], kf, s[mi][nj], 0, 0, 0);
      }
    }
    // scale + causal mask + per-row max
    float pm[2][4];
#pragma unroll
    for (int mi = 0; mi < 2; ++mi)
#pragma unroll
      for (int e = 0; e < 4; ++e) pm[mi][e] = -__builtin_inff();
#pragma unroll
    for (int mi = 0; mi < 2; ++mi)
#pragma unroll
      for (int nj = 0; nj < 4; ++nj)
#pragma unroll
        for (int e = 0; e < 4; ++e) {
          float v = s[mi][nj][e] * 0.125f;
          int r  = r0 + mi * 16 + g * 4 + e;
          int kv = j * 64 + nj * 16 + lr;
          v = (kv > r) ? -__builtin_inff() : v;
          s[mi][nj][e] = v;
          pm[mi][e] = fmaxf(pm[mi][e], v);
        }
#pragma unroll
    for (int off = 1; off < 16; off <<= 1)
#pragma unroll
      for (int mi = 0; mi < 2; ++mi)
#pragma unroll
        for (int e = 0; e < 4; ++e)
          pm[mi][e] = fmaxf(pm[mi][e], __shfl_xor(pm[mi][e], off));

    // online-softmax update
    float rs[2][4];
#pragma unroll
    for (int mi = 0; mi < 2; ++mi)
#pragma unroll
      for (int e = 0; e < 4; ++e) {
        float mn = fmaxf(m_run[mi][e], pm[mi][e]);
        float alpha = __expf(m_run[mi][e] - mn);   // first tile: exp(-inf)=0
        m_run[mi][e] = mn;
        l_run[mi][e] *= alpha;
        rs[mi][e] = 0.f;
#pragma unroll
        for (int nh = 0; nh < 4; ++nh) o[mi][nh][e] *= alpha;
      }
#pragma unroll
    for (int mi = 0; mi < 2; ++mi)
#pragma unroll
      for (int nj = 0; nj < 4; ++nj)
#pragma unroll
        for (int e = 0; e < 4; ++e) {
          float p = __expf(s[mi][nj][e] - m_run[mi][e]);  // masked: exp(-inf)=0
          s[mi][nj][e] = p;
          rs[mi][e] += p;
        }
#pragma unroll
    for (int off = 1; off < 16; off <<= 1)
#pragma unroll
      for (int mi = 0; mi < 2; ++mi)
#pragma unroll
        for (int e = 0; e < 4; ++e)
          rs[mi][e] += __shfl_xor(rs[mi][e], off);
#pragma unroll
    for (int mi = 0; mi < 2; ++mi)
#pragma unroll
      for (int e = 0; e < 4; ++e) l_run[mi][e] += rs[mi][e];

    // write P tile to wave-private slab (D layout -> [32][64] sw64)
#pragma unroll
    for (int mi = 0; mi < 2; ++mi)
#pragma unroll
      for (int nj = 0; nj < 4; ++nj)
#pragma unroll
        for (int e = 0; e < 4; ++e) {
          int rr = mi * 16 + g * 4 + e;
          int cc = nj * 16 + lr;
          pw[sw64(rr, cc)] = f2b(s[mi][nj][e]);
        }
    // wave-local LDS fence (no __syncthreads: waves have divergent j-trip counts)
    asm volatile("s_waitcnt lgkmcnt(0)" ::: "memory");

    // O += P @ V_tile
#pragma unroll
    for (int kb = 0; kb < 2; ++kb) {
      bf16x8 pf[2];
#pragma unroll
      for (int mi = 0; mi < 2; ++mi)
        pf[mi] = *reinterpret_cast<const bf16x8*>(&pw[sw64(mi * 16 + lr, kb * 32 + g * 8)]);
#pragma unroll
      for (int nh = 0; nh < 4; ++nh) {
        bf16x8 vf = *reinterpret_cast<const bf16x8*>(&vT[sw256(nh * 16 + lr, j * 64 + kb * 32 + g * 8)]);
#pragma unroll
        for (int mi = 0; mi < 2; ++mi)
          o[mi][nh] = __builtin_amdgcn_mfma_f32_16x16x32_bf16(pf[mi], vf, o[mi][nh], 0, 0, 0);
      }
    }
  }

  // epilogue: normalize and store fp32
  float* ob = out + (size_t)b * (T_DIM * H_DIM);
  float linv[2][4];
#pragma unroll
  for (int mi = 0; mi < 2; ++mi)
#pragma unroll
    for (int e = 0; e < 4; ++e) linv[mi][e] = 1.f / l_run[mi][e];
#pragma unroll
  for (int mi = 0; mi < 2; ++mi)
#pragma unroll
    for (int nh = 0; nh < 4; ++nh)
#pragma unroll
      for (int e = 0; e < 4; ++e) {
        int r = r0 + mi * 16 + g * 4 + e;
        int h = nh * 16 + lr;
        ob[r * H_DIM + h] = o[mi][nh][e] * linv[mi][e];
      }
}

extern "C" void kernel_launch(void* const* d_in, const int* in_sizes, int n_in,
                              void* d_out, int out_size, void* d_ws, size_t ws_size,
                              hipStream_t stream) {
  const float* x  = (const float*)d_in[0];
  const float* Wk = (const float*)d_in[1];
  const float* Wq = (const float*)d_in[2];
  const float* Wv = (const float*)d_in[3];
  float* out = (float*)d_out;
  int B = in_sizes[0] / (T_DIM * C_DIM);   // 512
  head_fused<<<dim3(B), dim3(512), 0, stream>>>(x, Wk, Wq, Wv, out);
}

// Round 6
// 67.155 us; speedup vs baseline: 1.9267x; 1.2305x over previous
//
#include <hip/hip_runtime.h>

#define T_DIM 256
#define C_DIM 384
#define H_DIM 64

typedef __attribute__((ext_vector_type(4))) float f32x4;
typedef __attribute__((ext_vector_type(8))) short bf16x8;
typedef unsigned short u16;

// fp32 -> bf16 round-to-nearest-even (finite inputs)
__device__ __forceinline__ u16 f2b(float f) {
  unsigned u = __float_as_uint(f);
  u = (u + 0x7FFFu + ((u >> 16) & 1u)) >> 16;
  return (u16)u;
}

// Swizzled element offsets (u16 units). Writes and reads share the permutation.
__device__ __forceinline__ int sw64(int r, int c)  { return r * 64  + (c ^ ((r & 7) << 3)); }
__device__ __forceinline__ int sw256(int h, int t) { return h * 256 + (t ^ ((h & 7) << 3)); }
__device__ __forceinline__ int sw32(int r, int c)  { return r * 32  + (c ^ (((r >> 1) & 3) << 3)); }

// One block per batch. 512 threads = 8 waves.  (Round-2 structure restored;
// single change this round: W-staging task assignment is column-per-lane,
// killing the ~24-way bank conflicts on the wsT scalar stores.)
__global__ __launch_bounds__(512, 2)
void head_fused(const float* __restrict__ x,
                const float* __restrict__ Wk,
                const float* __restrict__ Wq,
                const float* __restrict__ Wv,
                float* __restrict__ out)
{
  __shared__ u16 qs[T_DIM * H_DIM];   // 32 KB  Q[t][h] bf16  (sw64)
  __shared__ u16 ks[T_DIM * H_DIM];   // 32 KB  K[t][h] bf16  (sw64)
  __shared__ u16 vT[H_DIM * T_DIM];   // 32 KB  V^T[h][t] bf16 (sw256)
  __shared__ u16 un[16384];           // 32 KB  phase1: xs[256][32]+wsT[192][32]; phase2: P slabs

  u16* xs  = un;          // [256][32] sw32
  u16* wsT = un + 8192;   // [192][32] sw32 (rows 0-63 Wq, 64-127 Wk, 128-191 Wv)

  const int tid  = threadIdx.x;
  const int wv   = tid >> 6;
  const int lane = tid & 63;
  const int g    = lane >> 4;
  const int lr   = lane & 15;
  const int b    = blockIdx.x;

  const float* xb = x + (size_t)b * (T_DIM * C_DIM);

  // ---------------- Phase 1: QKV projection ----------------
  int xr[4], xc[4];
#pragma unroll
  for (int it = 0; it < 4; ++it) {
    int idx = tid + it * 512;
    xr[it] = idx >> 3;
    xc[it] = (idx & 7) * 4;
  }
  // W staging: task idx -> row-quad q = idx>>5, col cc = idx&31 (lane-consecutive
  // columns -> the 4 scalar stores per task land 2-per-bank-pair, ~4-way max).
  int wrow[3], wcc[3];
  const float* wsrc[3];
#pragma unroll
  for (int it = 0; it < 3; ++it) {
    int idx = tid + it * 512;          // 0..1535
    int q   = idx >> 5;                // row-quad 0..47
    int cc  = idx & 31;                // col 0..31
    int seg = q >> 4;                  // 0:Q 1:K 2:V
    int hq  = q & 15;
    wrow[it] = seg * 64 + hq * 4;
    wcc[it]  = cc;
    wsrc[it] = ((seg == 0) ? Wq : (seg == 1) ? Wk : Wv) + hq * 4;
  }

  f32x4 acc[2][12];
#pragma unroll
  for (int mi = 0; mi < 2; ++mi)
#pragma unroll
    for (int nj = 0; nj < 12; ++nj)
      acc[mi][nj] = (f32x4){0.f, 0.f, 0.f, 0.f};

  // prefetch first tiles into registers
  f32x4 px[4], pwv[3];
#pragma unroll
  for (int it = 0; it < 4; ++it)
    px[it] = *reinterpret_cast<const f32x4*>(xb + xr[it] * C_DIM + xc[it]);
#pragma unroll
  for (int it = 0; it < 3; ++it)
    pwv[it] = *reinterpret_cast<const f32x4*>(wsrc[it] + wcc[it] * H_DIM);

  for (int kt = 0; kt < 12; ++kt) {
    __syncthreads();   // previous iteration's fragment reads done
    // write staged registers to LDS (swizzled)
#pragma unroll
    for (int it = 0; it < 4; ++it) {
      unsigned p0 = (unsigned)f2b(px[it][0]) | ((unsigned)f2b(px[it][1]) << 16);
      unsigned p1 = (unsigned)f2b(px[it][2]) | ((unsigned)f2b(px[it][3]) << 16);
      uint2 pv; pv.x = p0; pv.y = p1;
      *reinterpret_cast<uint2*>(&xs[sw32(xr[it], xc[it])]) = pv;
    }
#pragma unroll
    for (int it = 0; it < 3; ++it) {
      wsT[sw32(wrow[it] + 0, wcc[it])] = f2b(pwv[it][0]);
      wsT[sw32(wrow[it] + 1, wcc[it])] = f2b(pwv[it][1]);
      wsT[sw32(wrow[it] + 2, wcc[it])] = f2b(pwv[it][2]);
      wsT[sw32(wrow[it] + 3, wcc[it])] = f2b(pwv[it][3]);
    }
    // prefetch next K-chunk (latency hides under the MFMA section)
    if (kt < 11) {
      int kk = (kt + 1) * 32;
#pragma unroll
      for (int it = 0; it < 4; ++it)
        px[it] = *reinterpret_cast<const f32x4*>(xb + xr[it] * C_DIM + kk + xc[it]);
#pragma unroll
      for (int it = 0; it < 3; ++it)
        pwv[it] = *reinterpret_cast<const f32x4*>(wsrc[it] + (kk + wcc[it]) * H_DIM);
    }
    __syncthreads();

    // MFMA: wave wv computes rows [wv*32, wv*32+32), all 192 N cols
    bf16x8 afr[2];
#pragma unroll
    for (int mi = 0; mi < 2; ++mi)
      afr[mi] = *reinterpret_cast<const bf16x8*>(&xs[sw32(wv * 32 + mi * 16 + lr, g * 8)]);
#pragma unroll
    for (int nj = 0; nj < 12; ++nj) {
      bf16x8 bfr = *reinterpret_cast<const bf16x8*>(&wsT[sw32(nj * 16 + lr, g * 8)]);
#pragma unroll
      for (int mi = 0; mi < 2; ++mi)
        acc[mi][nj] = __builtin_amdgcn_mfma_f32_16x16x32_bf16(afr[mi], bfr, acc[mi][nj], 0, 0, 0);
    }
  }

  // scatter QKV fragments into LDS (D layout: row = 4g+e, col = lr), swizzled
#pragma unroll
  for (int mi = 0; mi < 2; ++mi)
#pragma unroll
    for (int nj = 0; nj < 12; ++nj)
#pragma unroll
      for (int e = 0; e < 4; ++e) {
        int r = wv * 32 + mi * 16 + g * 4 + e;
        int n = nj * 16 + lr;
        u16 val = f2b(acc[mi][nj][e]);
        if (n < 64)       qs[sw64(r, n)] = val;
        else if (n < 128) ks[sw64(r, n - 64)] = val;
        else              vT[sw256(n - 128, r)] = val;
      }
  __syncthreads();

  // ---------------- Phase 2: causal flash attention ----------------
  const int r0   = wv * 32;
  const int jmax = wv >> 1;          // last kv tile this wave needs
  u16* pw = un + wv * 2048;          // per-wave P slab [32][64] sw64

  bf16x8 qf[2][2];
#pragma unroll
  for (int mi = 0; mi < 2; ++mi)
#pragma unroll
    for (int kb = 0; kb < 2; ++kb)
      qf[mi][kb] = *reinterpret_cast<const bf16x8*>(&qs[sw64(r0 + mi * 16 + lr, kb * 32 + g * 8)]);

  f32x4 o[2][4];
  float m_run[2][4], l_run[2][4];
#pragma unroll
  for (int mi = 0; mi < 2; ++mi) {
#pragma unroll
    for (int e = 0; e < 4; ++e) { m_run[mi][e] = -__builtin_inff(); l_run[mi][e] = 0.f; }
#pragma unroll
    for (int nh = 0; nh < 4; ++nh) o[mi][nh] = (f32x4){0.f, 0.f, 0.f, 0.f};
  }

  for (int j = 0; j <= jmax; ++j) {
    // S tile [32][64] = Q rows x K tile^T
    f32x4 s[2][4];
#pragma unroll
    for (int mi = 0; mi < 2; ++mi)
#pragma unroll
      for (int nj = 0; nj < 4; ++nj)
        s[mi][nj] = (f32x4){0.f, 0.f, 0.f, 0.f};
#pragma unroll
    for (int kb = 0; kb < 2; ++kb) {
#pragma unroll
      for (int nj = 0; nj < 4; ++nj) {
        bf16x8 kf = *reinterpret_cast<const bf16x8*>(&ks[sw64(j * 64 + nj * 16 + lr, kb * 32 + g * 8)]);
#pragma unroll
        for (int mi = 0; mi < 2; ++mi)
          s[mi][nj] = __builtin_amdgcn_mfma_f32_16x16x32_bf16(qf[mi][kb], kf, s[mi][nj], 0, 0, 0);
      }
    }
    // scale + causal mask + per-row max
    float pm[2][4];
#pragma unroll
    for (int mi = 0; mi < 2; ++mi)
#pragma unroll
      for (int e = 0; e < 4; ++e) pm[mi][e] = -__builtin_inff();
#pragma unroll
    for (int mi = 0; mi < 2; ++mi)
#pragma unroll
      for (int nj = 0; nj < 4; ++nj)
#pragma unroll
        for (int e = 0; e < 4; ++e) {
          float v = s[mi][nj][e] * 0.125f;
          int r  = r0 + mi * 16 + g * 4 + e;
          int kv = j * 64 + nj * 16 + lr;
          v = (kv > r) ? -__builtin_inff() : v;
          s[mi][nj][e] = v;
          pm[mi][e] = fmaxf(pm[mi][e], v);
        }
#pragma unroll
    for (int off = 1; off < 16; off <<= 1)
#pragma unroll
      for (int mi = 0; mi < 2; ++mi)
#pragma unroll
        for (int e = 0; e < 4; ++e)
          pm[mi][e] = fmaxf(pm[mi][e], __shfl_xor(pm[mi][e], off));

    // online-softmax update
    float rs[2][4];
#pragma unroll
    for (int mi = 0; mi < 2; ++mi)
#pragma unroll
      for (int e = 0; e < 4; ++e) {
        float mn = fmaxf(m_run[mi][e], pm[mi][e]);
        float alpha = __expf(m_run[mi][e] - mn);   // first tile: exp(-inf)=0
        m_run[mi][e] = mn;
        l_run[mi][e] *= alpha;
        rs[mi][e] = 0.f;
#pragma unroll
        for (int nh = 0; nh < 4; ++nh) o[mi][nh][e] *= alpha;
      }
#pragma unroll
    for (int mi = 0; mi < 2; ++mi)
#pragma unroll
      for (int nj = 0; nj < 4; ++nj)
#pragma unroll
        for (int e = 0; e < 4; ++e) {
          float p = __expf(s[mi][nj][e] - m_run[mi][e]);  // masked: exp(-inf)=0
          s[mi][nj][e] = p;
          rs[mi][e] += p;
        }
#pragma unroll
    for (int off = 1; off < 16; off <<= 1)
#pragma unroll
      for (int mi = 0; mi < 2; ++mi)
#pragma unroll
        for (int e = 0; e < 4; ++e)
          rs[mi][e] += __shfl_xor(rs[mi][e], off);
#pragma unroll
    for (int mi = 0; mi < 2; ++mi)
#pragma unroll
      for (int e = 0; e < 4; ++e) l_run[mi][e] += rs[mi][e];

    // write P tile to wave-private slab (D layout -> [32][64] sw64)
#pragma unroll
    for (int mi = 0; mi < 2; ++mi)
#pragma unroll
      for (int nj = 0; nj < 4; ++nj)
#pragma unroll
        for (int e = 0; e < 4; ++e) {
          int rr = mi * 16 + g * 4 + e;
          int cc = nj * 16 + lr;
          pw[sw64(rr, cc)] = f2b(s[mi][nj][e]);
        }
    // wave-local LDS fence (no __syncthreads: waves have divergent j-trip counts)
    asm volatile("s_waitcnt lgkmcnt(0)" ::: "memory");

    // O += P @ V_tile
#pragma unroll
    for (int kb = 0; kb < 2; ++kb) {
      bf16x8 pf[2];
#pragma unroll
      for (int mi = 0; mi < 2; ++mi)
        pf[mi] = *reinterpret_cast<const bf16x8*>(&pw[sw64(mi * 16 + lr, kb * 32 + g * 8)]);
#pragma unroll
      for (int nh = 0; nh < 4; ++nh) {
        bf16x8 vf = *reinterpret_cast<const bf16x8*>(&vT[sw256(nh * 16 + lr, j * 64 + kb * 32 + g * 8)]);
#pragma unroll
        for (int mi = 0; mi < 2; ++mi)
          o[mi][nh] = __builtin_amdgcn_mfma_f32_16x16x32_bf16(pf[mi], vf, o[mi][nh], 0, 0, 0);
      }
    }
  }

  // epilogue: normalize and store fp32
  float* ob = out + (size_t)b * (T_DIM * H_DIM);
  float linv[2][4];
#pragma unroll
  for (int mi = 0; mi < 2; ++mi)
#pragma unroll
    for (int e = 0; e < 4; ++e) linv[mi][e] = 1.f / l_run[mi][e];
#pragma unroll
  for (int mi = 0; mi < 2; ++mi)
#pragma unroll
    for (int nh = 0; nh < 4; ++nh)
#pragma unroll
      for (int e = 0; e < 4; ++e) {
        int r = r0 + mi * 16 + g * 4 + e;
        int h = nh * 16 + lr;
        ob[r * H_DIM + h] = o[mi][nh][e] * linv[mi][e];
      }
}

extern "C" void kernel_launch(void* const* d_in, const int* in_sizes, int n_in,
                              void* d_out, int out_size, void* d_ws, size_t ws_size,
                              hipStream_t stream) {
  const float* x  = (const float*)d_in[0];
  const float* Wk = (const float*)d_in[1];
  const float* Wq = (const float*)d_in[2];
  const float* Wv = (const float*)d_in[3];
  float* out = (float*)d_out;
  int B = in_sizes[0] / (T_DIM * C_DIM);   // 512
  head_fused<<<dim3(B), dim3(512), 0, stream>>>(x, Wk, Wq, Wv, out);
}